// Round 1
// baseline (8238.204 us; speedup 1.0000x reference)
//
#include <hip/hip_runtime.h>
#include <math.h>

#define E  512
#define NH 8
#define HDIM 64
#define FF 32
#define NL 3
#define NV 32000
#define NB 128
#define NT 16

// ---------------------------------------------------------------- pe table
__global__ void pe_init_kernel(float* __restrict__ pe) {
    int i = blockIdx.x;  // position 0..15
    for (int e = threadIdx.x; e < E; e += blockDim.x) {
        int k = e >> 1;
        double dv = exp((double)(2 * k) * (-log(10000.0) / (double)E));
        double arg = (double)i * dv;
        pe[i * E + e] = (e & 1) ? (float)cos(arg) : (float)sin(arg);
    }
}

// ------------------------------------------------------- tok_before row 0
__global__ void init_tok_kernel(float* __restrict__ tb, const float* __restrict__ emb) {
    int b = blockIdx.x;
    for (int e = threadIdx.x; e < E; e += blockDim.x)
        tb[(size_t)b * E + e] = emb[(size_t)1 * E + e];  // SOS = 1
}

// ------------------------------------------- C[M,N] = A[M,K] @ W[N,K]^T + bias
// 64x64 tile, BK=16, 4x4 per thread, 256 threads.
__global__ __launch_bounds__(256) void gemm_nt_kernel(
    const float* __restrict__ A, const float* __restrict__ W,
    const float* __restrict__ bias, float* __restrict__ C,
    int M, int N, int K)
{
    __shared__ float As[16][64];
    __shared__ float Ws[16][64];
    const int tid = threadIdx.x;
    const int tm = (tid >> 4) << 2;       // 0..60 step 4
    const int tn = (tid & 15) << 2;       // 0..60 step 4
    const int m0 = blockIdx.y * 64;
    const int n0 = blockIdx.x * 64;
    const int lr = tid >> 2;              // 0..63
    const int lc = (tid & 3) << 2;        // 0,4,8,12

    float acc[4][4] = {};
    for (int k0 = 0; k0 < K; k0 += 16) {
        float4 av = make_float4(0.f, 0.f, 0.f, 0.f);
        float4 wv = av;
        int am = m0 + lr;
        if (am < M) av = *(const float4*)&A[(size_t)am * K + k0 + lc];
        int wn = n0 + lr;
        if (wn < N) wv = *(const float4*)&W[(size_t)wn * K + k0 + lc];
        As[lc + 0][lr] = av.x; As[lc + 1][lr] = av.y; As[lc + 2][lr] = av.z; As[lc + 3][lr] = av.w;
        Ws[lc + 0][lr] = wv.x; Ws[lc + 1][lr] = wv.y; Ws[lc + 2][lr] = wv.z; Ws[lc + 3][lr] = wv.w;
        __syncthreads();
#pragma unroll
        for (int k = 0; k < 16; ++k) {
            float4 a4 = *(const float4*)&As[k][tm];
            float4 w4 = *(const float4*)&Ws[k][tn];
            float ar[4] = {a4.x, a4.y, a4.z, a4.w};
            float wr[4] = {w4.x, w4.y, w4.z, w4.w};
#pragma unroll
            for (int ii = 0; ii < 4; ++ii)
#pragma unroll
                for (int jj = 0; jj < 4; ++jj)
                    acc[ii][jj] += ar[ii] * wr[jj];
        }
        __syncthreads();
    }
#pragma unroll
    for (int ii = 0; ii < 4; ++ii) {
        int m = m0 + tm + ii;
        if (m >= M) continue;
#pragma unroll
        for (int jj = 0; jj < 4; ++jj) {
            int n = n0 + tn + jj;
            if (n < N) C[(size_t)m * N + n] = acc[ii][jj] + bias[n];
        }
    }
}

// -------------------------------------------------------- self attention
// qkv layout: [(s*NB+b)*3E + {0|E|2E} + h*64 + d]. grid = NB*NH, block = 128.
__global__ __launch_bounds__(128) void attn_kernel(
    const float* __restrict__ qkv, float* __restrict__ o, int S)
{
    const int b = blockIdx.x >> 3;
    const int h = blockIdx.x & 7;
    __shared__ float Ks[16][64];
    __shared__ float Vs[16][64];
    const int tid = threadIdx.x;
    for (int idx = tid; idx < S * 64; idx += 128) {
        int s = idx >> 6, d = idx & 63;
        size_t base = ((size_t)(s * NB + b)) * (3 * E) + h * 64 + d;
        Ks[s][d] = qkv[base + E];
        Vs[s][d] = qkv[base + 2 * E];
    }
    __syncthreads();
    const int wid = tid >> 6, lane = tid & 63;
    for (int qi = wid; qi < S; qi += 2) {
        float qd = qkv[((size_t)(qi * NB + b)) * (3 * E) + h * 64 + lane];
        float sc[16];
#pragma unroll
        for (int ki = 0; ki < 16; ++ki) {
            float p = 0.f;
            if (ki < S) {
                p = qd * Ks[ki][lane];
#pragma unroll
                for (int off = 32; off; off >>= 1) p += __shfl_xor(p, off);
                p *= 0.125f;  // 1/sqrt(64)
            }
            sc[ki] = p;
        }
        float m = -1e30f;
#pragma unroll
        for (int ki = 0; ki < 16; ++ki) if (ki < S) m = fmaxf(m, sc[ki]);
        float sum = 0.f;
#pragma unroll
        for (int ki = 0; ki < 16; ++ki) if (ki < S) { sc[ki] = expf(sc[ki] - m); sum += sc[ki]; }
        float inv = 1.0f / sum;
        float acc = 0.f;
#pragma unroll
        for (int ki = 0; ki < 16; ++ki) if (ki < S) acc += sc[ki] * Vs[ki][lane];
        o[((size_t)(qi * NB + b)) * E + h * 64 + lane] = acc * inv;
    }
}

// ------------------------- x = LN(LN(xin + y; g0,b0) + ca; g1,b1), row-wise
__global__ __launch_bounds__(256) void lnln_kernel(
    const float* __restrict__ xin, const float* __restrict__ y,
    const float* __restrict__ ca,
    const float* __restrict__ g0, const float* __restrict__ b0,
    const float* __restrict__ g1, const float* __restrict__ b1,
    float* __restrict__ xout, int rows)
{
    const int wid = threadIdx.x >> 6, lane = threadIdx.x & 63;
    const int row = blockIdx.x * 4 + wid;
    if (row >= rows) return;
    const float* xr = xin + (size_t)row * E;
    const float* yr = y + (size_t)row * E;
    const float* cr = ca + (size_t)(row & (NB - 1)) * E;
    float v[8];
    float s = 0.f;
#pragma unroll
    for (int j = 0; j < 8; ++j) { int e = j * 64 + lane; v[j] = xr[e] + yr[e]; s += v[j]; }
#pragma unroll
    for (int off = 32; off; off >>= 1) s += __shfl_xor(s, off);
    float mean = s * (1.0f / E);
    float vs = 0.f;
#pragma unroll
    for (int j = 0; j < 8; ++j) { float d = v[j] - mean; vs += d * d; }
#pragma unroll
    for (int off = 32; off; off >>= 1) vs += __shfl_xor(vs, off);
    float rstd = rsqrtf(vs * (1.0f / E) + 1e-5f);
#pragma unroll
    for (int j = 0; j < 8; ++j) {
        int e = j * 64 + lane;
        v[j] = (v[j] - mean) * rstd * g0[e] + b0[e] + cr[e];
    }
    // second LN
    s = 0.f;
#pragma unroll
    for (int j = 0; j < 8; ++j) s += v[j];
#pragma unroll
    for (int off = 32; off; off >>= 1) s += __shfl_xor(s, off);
    mean = s * (1.0f / E);
    vs = 0.f;
#pragma unroll
    for (int j = 0; j < 8; ++j) { float d = v[j] - mean; vs += d * d; }
#pragma unroll
    for (int off = 32; off; off >>= 1) vs += __shfl_xor(vs, off);
    rstd = rsqrtf(vs * (1.0f / E) + 1e-5f);
#pragma unroll
    for (int j = 0; j < 8; ++j) {
        int e = j * 64 + lane;
        xout[(size_t)row * E + e] = (v[j] - mean) * rstd * g1[e] + b1[e];
    }
}

// ---------- fused FFN: x = LN(x + relu(x@W1^T+b1)@W2^T+b2; g2,bb2), wave/row
__global__ __launch_bounds__(256) void ffn_kernel(
    const float* __restrict__ x,
    const float* __restrict__ w1, const float* __restrict__ b1,
    const float* __restrict__ w2, const float* __restrict__ b2,
    const float* __restrict__ g2, const float* __restrict__ bb2,
    float* __restrict__ xout, int rows)
{
    const int wid = threadIdx.x >> 6, lane = threadIdx.x & 63;
    const int row = blockIdx.x * 4 + wid;
    if (row >= rows) return;
    const float* xr = x + (size_t)row * E;
    float v[8];
#pragma unroll
    for (int j = 0; j < 8; ++j) v[j] = xr[j * 64 + lane];
    float h[FF];
#pragma unroll
    for (int f = 0; f < FF; ++f) {
        float p = 0.f;
#pragma unroll
        for (int j = 0; j < 8; ++j) p += v[j] * w1[(size_t)f * E + j * 64 + lane];
#pragma unroll
        for (int off = 32; off; off >>= 1) p += __shfl_xor(p, off);
        h[f] = fmaxf(p + b1[f], 0.f);
    }
    float o[8];
#pragma unroll
    for (int j = 0; j < 8; ++j) {
        int e = j * 64 + lane;
        float acc = b2[e];
#pragma unroll
        for (int f4 = 0; f4 < FF / 4; ++f4) {
            float4 w4 = *(const float4*)&w2[(size_t)e * FF + f4 * 4];
            acc += h[f4 * 4 + 0] * w4.x + h[f4 * 4 + 1] * w4.y +
                   h[f4 * 4 + 2] * w4.z + h[f4 * 4 + 3] * w4.w;
        }
        o[j] = v[j] + acc;  // residual
    }
    float s = 0.f;
#pragma unroll
    for (int j = 0; j < 8; ++j) s += o[j];
#pragma unroll
    for (int off = 32; off; off >>= 1) s += __shfl_xor(s, off);
    float mean = s * (1.0f / E);
    float vs = 0.f;
#pragma unroll
    for (int j = 0; j < 8; ++j) { float d = o[j] - mean; vs += d * d; }
#pragma unroll
    for (int off = 32; off; off >>= 1) vs += __shfl_xor(vs, off);
    float rstd = rsqrtf(vs * (1.0f / E) + 1e-5f);
#pragma unroll
    for (int j = 0; j < 8; ++j) {
        int e = j * 64 + lane;
        xout[(size_t)row * E + e] = (o[j] - mean) * rstd * g2[e] + bb2[e];
    }
}

// ------- softmax over V per row + argmax token + append emb[tok]+pe row
__global__ __launch_bounds__(256) void softmax_kernel(
    float* __restrict__ probs,          // logits in, probs out (b*NV rows)
    float* __restrict__ tok_out,        // d_out tokens area
    const float* __restrict__ emb,
    const float* __restrict__ pe_row,   // pe + step*E
    float* __restrict__ tb_new,         // tok_before + S*NB*E
    int step)
{
    const int b = blockIdx.x, t = threadIdx.x;
    float* L = probs + (size_t)b * NV;
    float vmax = -1e30f; int imax = 0;
    for (int idx = t; idx < NV; idx += 256) {
        float val = L[idx];
        if (val > vmax) { vmax = val; imax = idx; }
    }
    __shared__ float sv[256];
    __shared__ int si[256];
    sv[t] = vmax; si[t] = imax;
    __syncthreads();
    for (int off = 128; off; off >>= 1) {
        if (t < off) {
            if (sv[t + off] > sv[t] || (sv[t + off] == sv[t] && si[t + off] < si[t])) {
                sv[t] = sv[t + off]; si[t] = si[t + off];
            }
        }
        __syncthreads();
    }
    const float m = sv[0];
    const int tok = si[0];
    __syncthreads();
    float psum = 0.f;
    for (int idx = t; idx < NV; idx += 256) psum += expf(L[idx] - m);
    sv[t] = psum;
    __syncthreads();
    for (int off = 128; off; off >>= 1) {
        if (t < off) sv[t] += sv[t + off];
        __syncthreads();
    }
    const float inv = 1.0f / sv[0];
    for (int idx = t; idx < NV; idx += 256) L[idx] = expf(L[idx] - m) * inv;
    if (t == 0) tok_out[(size_t)b * NT + step] = (float)tok;
    for (int e = t; e < E; e += 256)
        tb_new[(size_t)b * E + e] = emb[(size_t)tok * E + e] + pe_row[e];
}

// ================================================================ host
extern "C" void kernel_launch(void* const* d_in, const int* in_sizes, int n_in,
                              void* d_out, int out_size, void* d_ws, size_t ws_size,
                              hipStream_t stream) {
    const float* cur_room = (const float*)d_in[0];
    const float* emb      = (const float*)d_in[1];
    const float* sa_in_w  = (const float*)d_in[2];
    const float* sa_in_b  = (const float*)d_in[3];
    const float* sa_out_w = (const float*)d_in[4];
    const float* sa_out_b = (const float*)d_in[5];
    const float* ca_in_w  = (const float*)d_in[6];
    const float* ca_in_b  = (const float*)d_in[7];
    const float* ca_out_w = (const float*)d_in[8];
    const float* ca_out_b = (const float*)d_in[9];
    const float* ff1_w    = (const float*)d_in[10];
    const float* ff1_b    = (const float*)d_in[11];
    const float* ff2_w    = (const float*)d_in[12];
    const float* ff2_b    = (const float*)d_in[13];
    const float* ln_g     = (const float*)d_in[14];
    const float* ln_b     = (const float*)d_in[15];
    const float* out_w    = (const float*)d_in[16];
    const float* out_b    = (const float*)d_in[17];
    float* out = (float*)d_out;

    float* ws = (float*)d_ws;
    float* pe       = ws;                                  // 16*E
    float* ca_const = pe + 16 * E;                         // NL*NB*E
    float* tokb     = ca_const + (size_t)NL * NB * E;      // 17*NB*E
    float* x        = tokb + (size_t)17 * NB * E;          // 16*NB*E
    float* qkvb     = x + (size_t)16 * NB * E;             // 16*NB*3E
    float* attn_o   = qkvb + (size_t)16 * NB * 3 * E;      // 16*NB*E
    float* ybuf     = attn_o + (size_t)16 * NB * E;        // 16*NB*E
    float* hv       = ybuf + (size_t)16 * NB * E;          // NB*E

    pe_init_kernel<<<16, 256, 0, stream>>>(pe);
    init_tok_kernel<<<NB, 256, 0, stream>>>(tokb, emb);

    // cross-attention constants: ca_const[l] = (hx @ Wv^T + bv) @ Wout^T + bout
    for (int l = 0; l < NL; ++l) {
        const float* wv = ca_in_w + ((size_t)l * 3 * E + 2 * E) * E;
        const float* bv = ca_in_b + (size_t)l * 3 * E + 2 * E;
        gemm_nt_kernel<<<dim3(E / 64, NB / 64), 256, 0, stream>>>(
            cur_room, wv, bv, hv, NB, E, E);
        gemm_nt_kernel<<<dim3(E / 64, NB / 64), 256, 0, stream>>>(
            hv, ca_out_w + (size_t)l * E * E, ca_out_b + (size_t)l * E,
            ca_const + (size_t)l * NB * E, NB, E, E);
    }

    for (int i = 0; i < NT; ++i) {
        const int S = i + 1;
        const int M = S * NB;
        for (int l = 0; l < NL; ++l) {
            const float* xin = (l == 0) ? tokb : x;
            gemm_nt_kernel<<<dim3(3 * E / 64, M / 64), 256, 0, stream>>>(
                xin, sa_in_w + (size_t)l * 3 * E * E, sa_in_b + (size_t)l * 3 * E,
                qkvb, M, 3 * E, E);
            attn_kernel<<<NB * NH, 128, 0, stream>>>(qkvb, attn_o, S);
            gemm_nt_kernel<<<dim3(E / 64, M / 64), 256, 0, stream>>>(
                attn_o, sa_out_w + (size_t)l * E * E, sa_out_b + (size_t)l * E,
                ybuf, M, E, E);
            lnln_kernel<<<S * 32, 256, 0, stream>>>(
                xin, ybuf, ca_const + (size_t)l * NB * E,
                ln_g + (size_t)(l * 3 + 0) * E, ln_b + (size_t)(l * 3 + 0) * E,
                ln_g + (size_t)(l * 3 + 1) * E, ln_b + (size_t)(l * 3 + 1) * E,
                x, M);
            ffn_kernel<<<S * 32, 256, 0, stream>>>(
                x, ff1_w + (size_t)l * FF * E, ff1_b + (size_t)l * FF,
                ff2_w + (size_t)l * E * FF, ff2_b + (size_t)l * E,
                ln_g + (size_t)(l * 3 + 2) * E, ln_b + (size_t)(l * 3 + 2) * E,
                x, M);
        }
        float* probs = out + 2048 + (size_t)i * NB * NV;
        gemm_nt_kernel<<<dim3(NV / 64, NB / 64), 256, 0, stream>>>(
            x + (size_t)(S - 1) * NB * E, out_w, out_b, probs, NB, NV, E);
        softmax_kernel<<<NB, 256, 0, stream>>>(
            probs, out, emb, pe + (size_t)i * E, tokb + (size_t)S * NB * E, i);
    }
}